// Round 4
// baseline (291.104 us; speedup 1.0000x reference)
//
#include <hip/hip_runtime.h>

typedef __attribute__((ext_vector_type(8))) short bf16x8;   // 8 bf16 (4 VGPRs)
typedef __attribute__((ext_vector_type(4))) float f32x4;    // MFMA C/D
typedef unsigned short u16;
typedef unsigned int u32;

__device__ __forceinline__ float bf2f(u16 x) {
  union { u32 u; float f; } v; v.u = ((u32)x) << 16; return v.f;
}
__device__ __forceinline__ u16 f2b(float f) {
  union { float f; u32 u; } v; v.f = f;
  return (u16)((v.u + 0x7FFFu + ((v.u >> 16) & 1u)) >> 16);
}
// q_mask is all ones: fp32 word0 = 0x3F800000, packed-bf16 word0 = 0x3F803F80
__device__ __forceinline__ bool inputs_are_bf16(const void* qmask) {
  return *(const u32*)qmask == 0x3F803F80u;
}

// ---------------- prep: convert q,a -> bf16 ws, transpose U -> Ut (bf16), zero stats ----
__global__ __launch_bounds__(256) void prep_all(
    const void* __restrict__ q, const void* __restrict__ a,
    const void* __restrict__ U, const void* __restrict__ qmask,
    u16* __restrict__ qb, u16* __restrict__ ab, u16* __restrict__ Ut,
    float* __restrict__ stats)
{
  const bool bf = inputs_are_bf16(qmask);
  const int t = threadIdx.x;
  __shared__ u16 tile[64][65];
  if (blockIdx.x < 8192) {
    const int idx = blockIdx.x * 256 + t;           // [0, 2097152)
    if (idx < 131072) stats[idx] = 0.f;             // rowmax,rowsum,colmax,colsum
    const size_t base = (size_t)idx * 8;
    if (bf) {
      *(bf16x8*)&qb[base] = ((const bf16x8*)q)[idx];
      *(bf16x8*)&ab[base] = ((const bf16x8*)a)[idx];
    } else {
      const float4* qf = (const float4*)q;
      const float4* af = (const float4*)a;
      float4 x0 = qf[2 * idx], x1 = qf[2 * idx + 1];
      u16 o[8] = {f2b(x0.x), f2b(x0.y), f2b(x0.z), f2b(x0.w),
                  f2b(x1.x), f2b(x1.y), f2b(x1.z), f2b(x1.w)};
      *(bf16x8*)&qb[base] = *(bf16x8*)o;
      float4 y0 = af[2 * idx], y1 = af[2 * idx + 1];
      u16 p[8] = {f2b(y0.x), f2b(y0.y), f2b(y0.z), f2b(y0.w),
                  f2b(y1.x), f2b(y1.y), f2b(y1.z), f2b(y1.w)};
      *(bf16x8*)&ab[base] = *(bf16x8*)p;
    }
  } else {
    const int bb = blockIdx.x - 8192;               // [0,64)
    const int bx = bb & 7, by = bb >> 3;
    #pragma unroll
    for (int i = 0; i < 16; i++) {
      int r = i * 4 + (t >> 6);
      int c = t & 63;
      size_t gi = (size_t)(by * 64 + r) * 512 + bx * 64 + c;
      tile[c][r] = bf ? ((const u16*)U)[gi] : f2b(((const float*)U)[gi]);
    }
    __syncthreads();
    #pragma unroll
    for (int i = 0; i < 16; i++) {
      int r = i * 4 + (t >> 6);
      int c = t & 63;
      Ut[(size_t)(bx * 64 + r) * 512 + by * 64 + c] = tile[r][c];
    }
  }
}

// ---------------- 128x128 bf16 MFMA GEMM, C = A * B^T (both [rows x 512] bf16 row-major) ----
// Staging: global_load_lds width=16, XOR-swizzled 128x64 LDS tiles (no padding, no ds_write,
// conflict-free b128 fragment reads: phys chunk c_p of row r holds logical chunk c_p ^ (r&7)).
// EPI==0: write C (bf16, ldc=512).  EPI==1: fused sigmoid/exp + row/col stats via atomics.
template<int EPI>
__global__ __launch_bounds__(256) void gemm_bt(
    const u16* __restrict__ A, const u16* __restrict__ B,
    u16* __restrict__ C,
    size_t strideA, size_t strideB,
    const void* __restrict__ q_mask, const void* __restrict__ a_mask,
    float* __restrict__ rowmax, float* __restrict__ rowsum,
    float* __restrict__ colmax, float* __restrict__ colsum)
{
  __shared__ __align__(16) u16 As[128 * 64];
  __shared__ __align__(16) u16 Bs[128 * 64];
  __shared__ float qm[128], am[128];

  const int tid  = threadIdx.x;
  const int lane = tid & 63;
  const int wave = tid >> 6;
  const int wr = wave >> 1, wc = wave & 1;   // 2x2 wave grid, 64x64 each
  const int l15 = lane & 15, lq = lane >> 4; // lane-in-16, quad
  const int rsub = lane >> 3;                // staging: row within 8-row group
  const int csw  = (lane & 7) ^ rsub;        // staging: swizzled logical chunk

  const u16* Ab = A + strideA * blockIdx.z + (size_t)blockIdx.y * 128 * 512;
  const u16* Bb = B + strideB * blockIdx.z + (size_t)blockIdx.x * 128 * 512;

  if (EPI) {
    const bool bf = inputs_are_bf16(q_mask);
    if (tid < 128) {
      int gi = blockIdx.z * 1024 + blockIdx.y * 128 + tid;
      qm[tid] = bf ? bf2f(((const u16*)q_mask)[gi]) : ((const float*)q_mask)[gi];
    } else if (tid < 256) {
      int gj = blockIdx.z * 1024 + blockIdx.x * 128 + (tid - 128);
      am[tid - 128] = bf ? bf2f(((const u16*)a_mask)[gj]) : ((const float*)a_mask)[gj];
    }
  }

  f32x4 acc[4][4];
  #pragma unroll
  for (int i = 0; i < 4; i++)
    #pragma unroll
    for (int j = 0; j < 4; j++) {
      f32x4 z = {0.f, 0.f, 0.f, 0.f};
      acc[i][j] = z;
    }

  for (int k0 = 0; k0 < 512; k0 += 64) {
    // each wave stages rows [wave*32, wave*32+32) of both tiles: 4+4 global_load_lds x16B
    #pragma unroll
    for (int i = 0; i < 4; i++) {
      const int r0 = wave * 32 + i * 8;
      const size_t go = (size_t)(r0 + rsub) * 512 + k0 + csw * 8;
      __builtin_amdgcn_global_load_lds(
          (const __attribute__((address_space(1))) void*)(Ab + go),
          (__attribute__((address_space(3))) void*)&As[r0 * 64], 16, 0, 0);
      __builtin_amdgcn_global_load_lds(
          (const __attribute__((address_space(1))) void*)(Bb + go),
          (__attribute__((address_space(3))) void*)&Bs[r0 * 64], 16, 0, 0);
    }
    __syncthreads();
    #pragma unroll
    for (int ks = 0; ks < 64; ks += 32) {
      const int cx = ((ks >> 3) + lq) ^ (l15 & 7);   // swizzled chunk for fragment read
      bf16x8 af[4], bfr[4];
      #pragma unroll
      for (int tt = 0; tt < 4; tt++) {
        af[tt]  = *(const bf16x8*)&As[(wr * 64 + tt * 16 + l15) * 64 + cx * 8];
        bfr[tt] = *(const bf16x8*)&Bs[(wc * 64 + tt * 16 + l15) * 64 + cx * 8];
      }
      #pragma unroll
      for (int mt = 0; mt < 4; mt++)
        #pragma unroll
        for (int nt = 0; nt < 4; nt++)
          acc[mt][nt] = __builtin_amdgcn_mfma_f32_16x16x32_bf16(af[mt], bfr[nt], acc[mt][nt], 0, 0, 0);
    }
    __syncthreads();
  }

  if (!EPI) {
    u16* Cb = C + (size_t)blockIdx.y * 128 * 512 + blockIdx.x * 128;
    #pragma unroll
    for (int mt = 0; mt < 4; mt++)
      #pragma unroll
      for (int nt = 0; nt < 4; nt++)
        #pragma unroll
        for (int r = 0; r < 4; r++) {
          int row = wr * 64 + mt * 16 + lq * 4 + r;   // C/D: row=(lane>>4)*4+reg
          int col = wc * 64 + nt * 16 + l15;          //      col=lane&15
          Cb[(size_t)row * 512 + col] = f2b(acc[mt][nt][r]);
        }
  } else {
    const int gi0 = blockIdx.z * 1024 + blockIdx.y * 128;
    const int gj0 = blockIdx.z * 1024 + blockIdx.x * 128;
    float cmax[4] = {0.f, 0.f, 0.f, 0.f};
    float csum[4] = {0.f, 0.f, 0.f, 0.f};
    #pragma unroll
    for (int mt = 0; mt < 4; mt++) {
      #pragma unroll
      for (int r = 0; r < 4; r++) {
        int lrow = wr * 64 + mt * 16 + lq * 4 + r;
        float vi = qm[lrow];
        float rmx = 0.f, rsm = 0.f;
        #pragma unroll
        for (int nt = 0; nt < 4; nt++) {
          int lcol = wc * 64 + nt * 16 + l15;
          float x = acc[mt][nt][r];
          bool valid = (vi * am[lcol]) > 0.f;
          float I = valid ? 1.f / (1.f + __expf(-x)) : 0.f;  // sigmoid(NEG) = 0
          float e = __expf(I);                                // masked still adds exp(0)=1
          rmx = fmaxf(rmx, I);
          rsm += e;
          cmax[nt] = fmaxf(cmax[nt], I);
          csum[nt] += e;
        }
        #pragma unroll
        for (int off = 1; off < 16; off <<= 1) {
          rmx = fmaxf(rmx, __shfl_xor(rmx, off, 16));
          rsm += __shfl_xor(rsm, off, 16);
        }
        if (l15 == 0) {
          atomicMax((u32*)&rowmax[gi0 + lrow], __float_as_uint(rmx));  // I >= 0 so uint order ok
          atomicAdd(&rowsum[gi0 + lrow], rsm);
        }
      }
    }
    #pragma unroll
    for (int nt = 0; nt < 4; nt++) {
      float cm = cmax[nt], cs = csum[nt];
      cm = fmaxf(cm, __shfl_xor(cm, 16, 64)); cs += __shfl_xor(cs, 16, 64);
      cm = fmaxf(cm, __shfl_xor(cm, 32, 64)); cs += __shfl_xor(cs, 32, 64);
      if (lane < 16) {
        int gj = gj0 + wc * 64 + nt * 16 + l15;
        atomicMax((u32*)&colmax[gj], __float_as_uint(cm));
        atomicAdd(&colsum[gj], cs);
      }
    }
  }
}

// ---------------- partial: out_part[seg] = sum_{i in seg} src[i][h] * att[i] ----------------
// grid (2, 8, 64): x = h-chunk, y = 128-row segment, z = b*2 + half
__global__ __launch_bounds__(256) void partial_kernel(
    const u16* __restrict__ qb, const u16* __restrict__ ab,
    const float* __restrict__ stats, float* __restrict__ outp)
{
  __shared__ float att[128];
  const int tid = threadIdx.x;
  const int hc = blockIdx.x, seg = blockIdx.y;
  const int b = blockIdx.z >> 1, half = blockIdx.z & 1;
  const float* mx = stats + half * 65536 + b * 1024 + seg * 128;          // rowmax / colmax
  const float* sm = stats + half * 65536 + 32768 + b * 1024 + seg * 128;  // rowsum / colsum
  if (tid < 128) att[tid] = __expf(mx[tid]) / sm[tid];
  __syncthreads();
  const u16* src = (half ? ab : qb) + (size_t)b * 524288 + (size_t)seg * 128 * 512;
  const int h = hc * 256 + tid;
  float acc = 0.f;
  #pragma unroll 8
  for (int i = 0; i < 128; i++) acc += bf2f(src[(size_t)i * 512 + h]) * att[i];
  outp[(size_t)seg * 32768 + half * 16384 + b * 512 + h] = acc;
}

// output is fp32 (reference output dtype = float32)
__global__ __launch_bounds__(256) void final_sum(const float* __restrict__ outp,
                                                 float* __restrict__ out) {
  const int idx = blockIdx.x * 256 + threadIdx.x;  // [0, 32768)
  float s = 0.f;
  #pragma unroll
  for (int k = 0; k < 8; k++) s += outp[(size_t)k * 32768 + idx];
  out[idx] = s;
}

extern "C" void kernel_launch(void* const* d_in, const int* in_sizes, int n_in,
                              void* d_out, int out_size, void* d_ws, size_t ws_size,
                              hipStream_t stream) {
  const void* q  = d_in[0];
  const void* a  = d_in[1];
  const void* U  = d_in[2];
  const void* qm = d_in[3];
  const void* am = d_in[4];
  float* out = (float*)d_out;

  char* ws = (char*)d_ws;
  u16* qb    = (u16*)ws;                       //  33,554,432 B
  u16* ab    = (u16*)(ws + 33554432);          //  33,554,432 B
  u16* qU    = (u16*)(ws + 67108864);          //  33,554,432 B
  u16* Ut    = (u16*)(ws + 100663296);         //     524,288 B
  float* stats = (float*)(ws + 101187584);     //     524,288 B
  float* outp  = (float*)(ws + 101711872);     //   1,048,576 B  (total ~102.8 MB)
  float* rowmax = stats;
  float* rowsum = stats + 32768;
  float* colmax = stats + 65536;
  float* colsum = stats + 98304;

  prep_all<<<dim3(8256), dim3(256), 0, stream>>>(q, a, U, qm, qb, ab, Ut, stats);
  // qU[32768x512] = qb[32768x512] @ Ut[512x512]^T
  gemm_bt<0><<<dim3(4, 256, 1), dim3(256), 0, stream>>>(
      qb, Ut, qU, (size_t)0, (size_t)0, qm, am, rowmax, rowsum, colmax, colsum);
  // per batch: X = qU[b] @ ab[b]^T, fused sigmoid/exp + stats
  gemm_bt<1><<<dim3(8, 8, 32), dim3(256), 0, stream>>>(
      qU, ab, (u16*)nullptr, (size_t)524288, (size_t)524288, qm, am, rowmax, rowsum, colmax, colsum);
  partial_kernel<<<dim3(2, 8, 64), dim3(256), 0, stream>>>(qb, ab, stats, outp);
  final_sum<<<dim3(128), dim3(256), 0, stream>>>(outp, out);
}

// Round 5
// 266.069 us; speedup vs baseline: 1.0941x; 1.0941x over previous
//
#include <hip/hip_runtime.h>

typedef __attribute__((ext_vector_type(8))) short bf16x8;   // 8 bf16 (4 VGPRs)
typedef __attribute__((ext_vector_type(4))) float f32x4;    // MFMA C/D
typedef unsigned short u16;
typedef unsigned int u32;

#define NLOG2E -1.44269504088896f   // -log2(e)
#define LOG2E   1.44269504088896f

__device__ __forceinline__ float bf2f(u16 x) {
  union { u32 u; float f; } v; v.u = ((u32)x) << 16; return v.f;
}
__device__ __forceinline__ u16 f2b(float f) {
  union { float f; u32 u; } v; v.f = f;
  return (u16)((v.u + 0x7FFFu + ((v.u >> 16) & 1u)) >> 16);
}
// q_mask is all ones: fp32 word0 = 0x3F800000, packed-bf16 word0 = 0x3F803F80
__device__ __forceinline__ bool inputs_are_bf16(const void* qmask) {
  return *(const u32*)qmask == 0x3F803F80u;
}
// order-preserving float -> u32 key (min float == min key)
__device__ __forceinline__ u32 fkey(float f) {
  u32 b = __float_as_uint(f);
  return (b >> 31) ? ~b : (b | 0x80000000u);
}
__device__ __forceinline__ float fkey_inv(u32 k) {
  u32 b = (k & 0x80000000u) ? (k ^ 0x80000000u) : ~k;
  return __uint_as_float(b);
}

// ---------------- prep: convert q,a -> bf16 ws, transpose U -> Ut (bf16), init stats ----
// stats layout (131072 words): [rowsum f32 x32768][colsum f32 x32768][rowkey u32][colkey u32]
__global__ __launch_bounds__(256) void prep_all(
    const void* __restrict__ q, const void* __restrict__ a,
    const void* __restrict__ U, const void* __restrict__ qmask,
    u16* __restrict__ qb, u16* __restrict__ ab, u16* __restrict__ Ut,
    u32* __restrict__ stats)
{
  const bool bf = inputs_are_bf16(qmask);
  const int t = threadIdx.x;
  __shared__ u16 tile[64][65];
  if (blockIdx.x < 8192) {
    const int idx = blockIdx.x * 256 + t;           // [0, 2097152)
    if (idx < 131072) stats[idx] = (idx < 65536) ? 0u : 0xFFFFFFFFu;
    const size_t base = (size_t)idx * 8;
    if (bf) {
      *(bf16x8*)&qb[base] = ((const bf16x8*)q)[idx];
      *(bf16x8*)&ab[base] = ((const bf16x8*)a)[idx];
    } else {
      const float4* qf = (const float4*)q;
      const float4* af = (const float4*)a;
      float4 x0 = qf[2 * idx], x1 = qf[2 * idx + 1];
      u16 o[8] = {f2b(x0.x), f2b(x0.y), f2b(x0.z), f2b(x0.w),
                  f2b(x1.x), f2b(x1.y), f2b(x1.z), f2b(x1.w)};
      *(bf16x8*)&qb[base] = *(bf16x8*)o;
      float4 y0 = af[2 * idx], y1 = af[2 * idx + 1];
      u16 p[8] = {f2b(y0.x), f2b(y0.y), f2b(y0.z), f2b(y0.w),
                  f2b(y1.x), f2b(y1.y), f2b(y1.z), f2b(y1.w)};
      *(bf16x8*)&ab[base] = *(bf16x8*)p;
    }
  } else {
    const int bb = blockIdx.x - 8192;               // [0,64)
    const int bx = bb & 7, by = bb >> 3;
    #pragma unroll
    for (int i = 0; i < 16; i++) {
      int r = i * 4 + (t >> 6);
      int c = t & 63;
      size_t gi = (size_t)(by * 64 + r) * 512 + bx * 64 + c;
      tile[c][r] = bf ? ((const u16*)U)[gi] : f2b(((const float*)U)[gi]);
    }
    __syncthreads();
    #pragma unroll
    for (int i = 0; i < 16; i++) {
      int r = i * 4 + (t >> 6);
      int c = t & 63;
      Ut[(size_t)(bx * 64 + r) * 512 + by * 64 + c] = tile[r][c];
    }
  }
}

// ---------------- 128x128 bf16 MFMA GEMM, C = A * B^T (both [rows x 512] bf16 row-major) ----
// Staging: global_load_lds width=16, XOR-swizzled 128x64 LDS tiles (no ds_write staging).
// EPI==0: write C = scaleC * (A B^T) as bf16 (ldc=512).
// EPI==1: y = MFMA output = -log2e * X; fused epilogue:
//   u=exp2(y+pen) (pen=0 valid / 1e30 masked), s=rcp(1+u)=sigmoid(X), e=exp2(log2e*s)=exp(I);
//   row/col sums of e via LDS transpose-reduce; row/col min of y via same (max I = f(min y)).
template<int EPI>
__global__ __launch_bounds__(256) void gemm_bt(
    const u16* __restrict__ A, const u16* __restrict__ B,
    u16* __restrict__ C, float scaleC,
    size_t strideA, size_t strideB,
    const void* __restrict__ q_mask, const void* __restrict__ a_mask,
    float* __restrict__ rowsumA, float* __restrict__ colsumA,
    u32* __restrict__ rowkeyA, u32* __restrict__ colkeyA)
{
  __shared__ __align__(16) char smem[33792];
  u16* As = (u16*)smem;                 // 16384 B (K-loop)
  u16* Bs = (u16*)(smem + 16384);       // 16384 B (K-loop)
  float* redS = (float*)smem;           // 128 x 33 f32 = 16896 B (epilogue, reuse)
  float* redM = (float*)(smem + 16896); // 128 x 33 f32 = 16896 B (epilogue, reuse)
  __shared__ float qp[128], ap[128];    // additive penalties: 0 valid / 1e30 masked

  const int tid  = threadIdx.x;
  const int lane = tid & 63;
  const int wave = tid >> 6;
  const int wr = wave >> 1, wc = wave & 1;   // 2x2 wave grid, 64x64 each
  const int l15 = lane & 15, lq = lane >> 4; // lane-in-16, quad
  const int rsub = lane >> 3;                // staging: row within 8-row group
  const int csw  = (lane & 7) ^ rsub;        // staging: swizzled logical chunk

  const u16* Ab = A + strideA * blockIdx.z + (size_t)blockIdx.y * 128 * 512;
  const u16* Bb = B + strideB * blockIdx.z + (size_t)blockIdx.x * 128 * 512;

  if (EPI) {
    const bool bf = inputs_are_bf16(q_mask);
    if (tid < 128) {
      int gi = blockIdx.z * 1024 + blockIdx.y * 128 + tid;
      float v = bf ? bf2f(((const u16*)q_mask)[gi]) : ((const float*)q_mask)[gi];
      qp[tid] = (v > 0.f) ? 0.f : 1e30f;
    } else if (tid < 256) {
      int gj = blockIdx.z * 1024 + blockIdx.x * 128 + (tid - 128);
      float v = bf ? bf2f(((const u16*)a_mask)[gj]) : ((const float*)a_mask)[gj];
      ap[tid - 128] = (v > 0.f) ? 0.f : 1e30f;
    }
  }

  f32x4 acc[4][4];
  #pragma unroll
  for (int i = 0; i < 4; i++)
    #pragma unroll
    for (int j = 0; j < 4; j++) {
      f32x4 z = {0.f, 0.f, 0.f, 0.f};
      acc[i][j] = z;
    }

  for (int k0 = 0; k0 < 512; k0 += 64) {
    #pragma unroll
    for (int i = 0; i < 4; i++) {
      const int r0 = wave * 32 + i * 8;
      const size_t go = (size_t)(r0 + rsub) * 512 + k0 + csw * 8;
      __builtin_amdgcn_global_load_lds(
          (const __attribute__((address_space(1))) void*)(Ab + go),
          (__attribute__((address_space(3))) void*)&As[r0 * 64], 16, 0, 0);
      __builtin_amdgcn_global_load_lds(
          (const __attribute__((address_space(1))) void*)(Bb + go),
          (__attribute__((address_space(3))) void*)&Bs[r0 * 64], 16, 0, 0);
    }
    __syncthreads();
    #pragma unroll
    for (int ks = 0; ks < 64; ks += 32) {
      const int cx = ((ks >> 3) + lq) ^ (l15 & 7);   // swizzled chunk for fragment read
      bf16x8 af[4], bfr[4];
      #pragma unroll
      for (int tt = 0; tt < 4; tt++) {
        af[tt]  = *(const bf16x8*)&As[(wr * 64 + tt * 16 + l15) * 64 + cx * 8];
        bfr[tt] = *(const bf16x8*)&Bs[(wc * 64 + tt * 16 + l15) * 64 + cx * 8];
      }
      #pragma unroll
      for (int mt = 0; mt < 4; mt++)
        #pragma unroll
        for (int nt = 0; nt < 4; nt++)
          acc[mt][nt] = __builtin_amdgcn_mfma_f32_16x16x32_bf16(af[mt], bfr[nt], acc[mt][nt], 0, 0, 0);
    }
    __syncthreads();
  }

  if (!EPI) {
    u16* Cb = C + (size_t)blockIdx.y * 128 * 512 + blockIdx.x * 128;
    #pragma unroll
    for (int mt = 0; mt < 4; mt++)
      #pragma unroll
      for (int nt = 0; nt < 4; nt++)
        #pragma unroll
        for (int r = 0; r < 4; r++) {
          int row = wr * 64 + mt * 16 + lq * 4 + r;   // C/D: row=(lane>>4)*4+reg
          int col = wc * 64 + nt * 16 + l15;          //      col=lane&15
          Cb[(size_t)row * 512 + col] = f2b(scaleC * acc[mt][nt][r]);
        }
  } else {
    const int gi0 = blockIdx.z * 1024 + blockIdx.y * 128;
    const int gj0 = blockIdx.z * 1024 + blockIdx.x * 128;
    float apen[4];
    #pragma unroll
    for (int nt = 0; nt < 4; nt++) apen[nt] = ap[wc * 64 + nt * 16 + l15];

    float csum[4] = {0.f, 0.f, 0.f, 0.f};
    float cmin[4] = {3e38f, 3e38f, 3e38f, 3e38f};
    #pragma unroll
    for (int mt = 0; mt < 4; mt++) {
      #pragma unroll
      for (int r = 0; r < 4; r++) {
        const int row = wr * 64 + mt * 16 + lq * 4 + r;
        const float rowpen = qp[row];
        float rsm = 0.f, rmn = 3e38f;
        #pragma unroll
        for (int nt = 0; nt < 4; nt++) {
          float y = acc[mt][nt][r] + (rowpen + apen[nt]);  // masked -> ~1e30
          float u = __builtin_amdgcn_exp2f(y);             // e^{-X} (inf if masked)
          float s = __builtin_amdgcn_rcpf(1.f + u);        // sigmoid(X) (0 if masked)
          float e = __builtin_amdgcn_exp2f(LOG2E * s);     // exp(I)    (1 if masked)
          rsm += e;
          csum[nt] += e;
          rmn = fminf(rmn, y);
          cmin[nt] = fminf(cmin[nt], y);
        }
        redS[row * 33 + l15 + 16 * wc] = rsm;
        redM[row * 33 + l15 + 16 * wc] = rmn;
      }
    }
    // col reduce across quads (lanes l15 + 16*lq hold same col)
    #pragma unroll
    for (int nt = 0; nt < 4; nt++) {
      float cs = csum[nt], cm = cmin[nt];
      cs += __shfl_xor(cs, 16); cm = fminf(cm, __shfl_xor(cm, 16));
      cs += __shfl_xor(cs, 32); cm = fminf(cm, __shfl_xor(cm, 32));
      if (lane < 16) {
        int gj = gj0 + wc * 64 + nt * 16 + l15;
        atomicAdd(&colsumA[gj], cs);
        atomicMin(&colkeyA[gj], fkey(cm));
      }
    }
    __syncthreads();
    // row reduce: 32 partials per row in LDS (stride 33 -> 2-way max, free)
    if (tid < 128) {
      float s = 0.f;
      #pragma unroll
      for (int j = 0; j < 32; j++) s += redS[tid * 33 + j];
      atomicAdd(&rowsumA[gi0 + tid], s);
    } else {
      const int row = tid - 128;
      float m = 3e38f;
      #pragma unroll
      for (int j = 0; j < 32; j++) m = fminf(m, redM[row * 33 + j]);
      atomicMin(&rowkeyA[gi0 + row], fkey(m));
    }
  }
}

// ---------------- partial: out_part[seg] = sum_{i in seg} src[i][h] * att[i] ----------------
// att[i] = exp(I_max)/sum, I_max = sigmoid(X_max) = rcp(1+exp2(y_min)), y_min from key
// grid (2, 8, 64): x = h-chunk, y = 128-row segment, z = b*2 + half
__global__ __launch_bounds__(256) void partial_kernel(
    const u16* __restrict__ qb, const u16* __restrict__ ab,
    const u32* __restrict__ stats, float* __restrict__ outp)
{
  __shared__ float att[128];
  const int tid = threadIdx.x;
  const int hc = blockIdx.x, seg = blockIdx.y;
  const int b = blockIdx.z >> 1, half = blockIdx.z & 1;
  const float* sm = (const float*)stats + half * 32768 + b * 1024 + seg * 128;
  const u32* ky = stats + 65536 + half * 32768 + b * 1024 + seg * 128;
  if (tid < 128) {
    float ymin = fkey_inv(ky[tid]);
    float Imax = __builtin_amdgcn_rcpf(1.f + __builtin_amdgcn_exp2f(ymin));
    att[tid] = __expf(Imax) * __builtin_amdgcn_rcpf(sm[tid]);
  }
  __syncthreads();
  const u16* src = (half ? ab : qb) + (size_t)b * 524288 + (size_t)seg * 128 * 512;
  const int h = hc * 256 + tid;
  float acc = 0.f;
  #pragma unroll 8
  for (int i = 0; i < 128; i++) acc += bf2f(src[(size_t)i * 512 + h]) * att[i];
  outp[(size_t)seg * 32768 + half * 16384 + b * 512 + h] = acc;
}

// output is fp32 (reference output dtype = float32)
__global__ __launch_bounds__(256) void final_sum(const float* __restrict__ outp,
                                                 float* __restrict__ out) {
  const int idx = blockIdx.x * 256 + threadIdx.x;  // [0, 32768)
  float s = 0.f;
  #pragma unroll
  for (int k = 0; k < 8; k++) s += outp[(size_t)k * 32768 + idx];
  out[idx] = s;
}

extern "C" void kernel_launch(void* const* d_in, const int* in_sizes, int n_in,
                              void* d_out, int out_size, void* d_ws, size_t ws_size,
                              hipStream_t stream) {
  const void* q  = d_in[0];
  const void* a  = d_in[1];
  const void* U  = d_in[2];
  const void* qm = d_in[3];
  const void* am = d_in[4];
  float* out = (float*)d_out;

  char* ws = (char*)d_ws;
  u16* qb    = (u16*)ws;                       //  33,554,432 B
  u16* ab    = (u16*)(ws + 33554432);          //  33,554,432 B
  u16* qU    = (u16*)(ws + 67108864);          //  33,554,432 B (holds -log2e * qU)
  u16* Ut    = (u16*)(ws + 100663296);         //     524,288 B
  u32* stats = (u32*)(ws + 101187584);         //     524,288 B
  float* outp  = (float*)(ws + 101711872);     //   1,048,576 B  (total ~102.8 MB)
  float* rowsumA = (float*)stats;
  float* colsumA = (float*)stats + 32768;
  u32* rowkeyA = stats + 65536;
  u32* colkeyA = stats + 98304;

  prep_all<<<dim3(8256), dim3(256), 0, stream>>>(q, a, U, qm, qb, ab, Ut, stats);
  // qU[32768x512] = -log2e * (qb @ Ut^T)
  gemm_bt<0><<<dim3(4, 256, 1), dim3(256), 0, stream>>>(
      qb, Ut, qU, NLOG2E, (size_t)0, (size_t)0, qm, am,
      rowsumA, colsumA, rowkeyA, colkeyA);
  // per batch: y = qU[b] @ ab[b]^T = -log2e * X, fused epilogue
  gemm_bt<1><<<dim3(8, 8, 32), dim3(256), 0, stream>>>(
      qU, ab, (u16*)nullptr, 1.f, (size_t)524288, (size_t)524288, qm, am,
      rowsumA, colsumA, rowkeyA, colkeyA);
  partial_kernel<<<dim3(2, 8, 64), dim3(256), 0, stream>>>(qb, ab, stats, outp);
  final_sum<<<dim3(128), dim3(256), 0, stream>>>(outp, out);
}